// Round 3
// baseline (1033.918 us; speedup 1.0000x reference)
//
#include <hip/hip_runtime.h>
#include <stdint.h>

typedef unsigned short ushort_t;

#define T_SEQ 2048
#define BATCH 4
#define NHEAD 12
#define CEMB 768
#define HDIM 64
#define C3 2304

// ---------- bf16 helpers ----------
__device__ __forceinline__ float b2f(ushort_t u) {
  return __uint_as_float(((uint32_t)u) << 16);
}
__device__ __forceinline__ ushort_t f2b(float f) {
  uint32_t u = __float_as_uint(f);
  uint32_t r = (u + 0x7fffu + ((u >> 16) & 1u)) >> 16;  // RNE
  return (ushort_t)r;
}

// ---------- fp32 -> bf16 bulk convert (8 elems/thread) ----------
__global__ __launch_bounds__(256) void cvt_x_k(const float* __restrict__ in,
                                               ushort_t* __restrict__ out) {
  const int i = blockIdx.x * 256 + threadIdx.x;
  float4 a = ((const float4*)in)[2 * i];
  float4 b = ((const float4*)in)[2 * i + 1];
  union { ushort_t u[8]; uint4 v; } p;
  p.u[0] = f2b(a.x); p.u[1] = f2b(a.y); p.u[2] = f2b(a.z); p.u[3] = f2b(a.w);
  p.u[4] = f2b(b.x); p.u[5] = f2b(b.y); p.u[6] = f2b(b.z); p.u[7] = f2b(b.w);
  ((uint4*)out)[i] = p.v;
}

// ---------- fused transpose + fp32->bf16: out[c][r] = bf16(in[r][c]) ----------
__global__ void transpose_cvt_k(const float* __restrict__ in, ushort_t* __restrict__ out,
                                int R, int C) {
  __shared__ ushort_t tile[32][33];
  const int c0 = blockIdx.x * 32, r0 = blockIdx.y * 32;
  for (int i = threadIdx.y; i < 32; i += 8)
    tile[i][threadIdx.x] = f2b(in[(size_t)(r0 + i) * C + c0 + threadIdx.x]);
  __syncthreads();
  for (int i = threadIdx.y; i < 32; i += 8)
    out[(size_t)(c0 + i) * R + r0 + threadIdx.x] = tile[threadIdx.x][i];
}

// ---------- MFMA GEMM: C[M,N] = A[M,K] * Bt[N,K]^T + bias ----------
typedef __bf16 bf16x8 __attribute__((ext_vector_type(8)));
typedef float f32x4 __attribute__((ext_vector_type(4)));

template <bool OUTF>
__global__ __launch_bounds__(256) void gemm_bt(const ushort_t* __restrict__ A,
                                               const ushort_t* __restrict__ Bt,
                                               const float* __restrict__ bias,
                                               void* __restrict__ Cv,
                                               int M, int N, int K) {
  __shared__ ushort_t As[128 * 32];
  __shared__ ushort_t Bs[128 * 32];
  const int tid = threadIdx.x;
  const int m0 = blockIdx.y * 128, n0 = blockIdx.x * 128;
  const int wid = tid >> 6, lane = tid & 63;
  const int quad = lane >> 4, l15 = lane & 15;
  const int wm = (wid >> 1) * 64, wn = (wid & 1) * 64;
  f32x4 acc[4][4] = {};

  const int e0 = tid * 8;
  const int e1 = e0 + 2048;
  const int r0s = e0 >> 5, c0s = e0 & 31;
  const int r1s = e1 >> 5, c1s = e1 & 31;

  for (int k0 = 0; k0 < K; k0 += 32) {
    __syncthreads();
    *(uint4*)&As[e0] = *(const uint4*)&A[(size_t)(m0 + r0s) * K + k0 + c0s];
    *(uint4*)&As[e1] = *(const uint4*)&A[(size_t)(m0 + r1s) * K + k0 + c1s];
    *(uint4*)&Bs[e0] = *(const uint4*)&Bt[(size_t)(n0 + r0s) * K + k0 + c0s];
    *(uint4*)&Bs[e1] = *(const uint4*)&Bt[(size_t)(n0 + r1s) * K + k0 + c1s];
    __syncthreads();
    bf16x8 af[4], bfr[4];
#pragma unroll
    for (int t = 0; t < 4; t++)
      af[t] = *(const bf16x8*)&As[(wm + t * 16 + l15) * 32 + quad * 8];
#pragma unroll
    for (int t = 0; t < 4; t++)
      bfr[t] = *(const bf16x8*)&Bs[(wn + t * 16 + l15) * 32 + quad * 8];
#pragma unroll
    for (int tm = 0; tm < 4; tm++)
#pragma unroll
      for (int tn = 0; tn < 4; tn++)
        acc[tm][tn] = __builtin_amdgcn_mfma_f32_16x16x32_bf16(af[tm], bfr[tn], acc[tm][tn], 0, 0, 0);
  }

#pragma unroll
  for (int tm = 0; tm < 4; tm++) {
    const int row = m0 + wm + tm * 16 + quad * 4;
#pragma unroll
    for (int tn = 0; tn < 4; tn++) {
      const int col = n0 + wn + tn * 16 + l15;
      const float bv = bias[col];
#pragma unroll
      for (int rr = 0; rr < 4; rr++) {
        if constexpr (OUTF)
          ((float*)Cv)[(size_t)(row + rr) * N + col] = acc[tm][tn][rr] + bv;
        else
          ((ushort_t*)Cv)[(size_t)(row + rr) * N + col] = f2b(acc[tm][tn][rr] + bv);
      }
    }
  }
}

// ---------- VALU flash attention (online softmax), causal ----------
#define KSTR 68  // fp32 LDS row stride

__global__ __launch_bounds__(256) void attn_k(const ushort_t* __restrict__ qkv,
                                              ushort_t* __restrict__ y) {
  __shared__ float Ksm[64 * KSTR];
  __shared__ float Vsm[64 * KSTR];
  __shared__ float Psm[64 * KSTR];
  const int qt = blockIdx.x, h = blockIdx.y, b = blockIdx.z;
  const int tid = threadIdx.x;
  const int q = tid >> 2;
  const int dq = tid & 3;
  const int q_glob = qt * 64 + q;

  // Q row into registers, pre-scaled by 1/sqrt(64)
  float qr[64];
  {
    const ushort_t* qp = qkv + ((size_t)(b * T_SEQ + q_glob)) * C3 + h * HDIM;
#pragma unroll
    for (int d0 = 0; d0 < 64; d0 += 8) {
      uint4 w = *(const uint4*)(qp + d0);
      uint32_t a[4] = {w.x, w.y, w.z, w.w};
#pragma unroll
      for (int jj = 0; jj < 4; jj++) {
        qr[d0 + 2 * jj]     = __uint_as_float(a[jj] << 16) * 0.125f;
        qr[d0 + 2 * jj + 1] = __uint_as_float(a[jj] & 0xffff0000u) * 0.125f;
      }
    }
  }

  float m_i = -1e30f, l_i = 0.f;
  float acc[16];
#pragma unroll
  for (int i = 0; i < 16; i++) acc[i] = 0.f;

  const int r = tid >> 2;
  const int c0 = (tid & 3) * 16;

  const int nkt = qt + 1;
  for (int kt = 0; kt < nkt; ++kt) {
    __syncthreads();
    {
      size_t base = ((size_t)(b * T_SEQ + kt * 64 + r)) * C3 + CEMB + h * HDIM + c0;
      uint4 k0v = *(const uint4*)(qkv + base);
      uint4 k1v = *(const uint4*)(qkv + base + 8);
      uint4 v0v = *(const uint4*)(qkv + base + CEMB);
      uint4 v1v = *(const uint4*)(qkv + base + CEMB + 8);
      float* kd = &Ksm[r * KSTR + c0];
      float* vd = &Vsm[r * KSTR + c0];
      uint32_t ka[8] = {k0v.x, k0v.y, k0v.z, k0v.w, k1v.x, k1v.y, k1v.z, k1v.w};
      uint32_t va[8] = {v0v.x, v0v.y, v0v.z, v0v.w, v1v.x, v1v.y, v1v.z, v1v.w};
#pragma unroll
      for (int jj = 0; jj < 8; jj++) {
        kd[2 * jj]     = __uint_as_float(ka[jj] << 16);
        kd[2 * jj + 1] = __uint_as_float(ka[jj] & 0xffff0000u);
        vd[2 * jj]     = __uint_as_float(va[jj] << 16);
        vd[2 * jj + 1] = __uint_as_float(va[jj] & 0xffff0000u);
      }
    }
    __syncthreads();

    float s[16];
    const bool diag = (kt == qt);
#pragma unroll
    for (int j = 0; j < 16; j++) {
      const int k = dq + 4 * j;
      const float* kp = &Ksm[k * KSTR];
      float sum = 0.f;
#pragma unroll
      for (int d0 = 0; d0 < 64; d0 += 4) {
        float4 kv = *(const float4*)(kp + d0);
        sum = fmaf(qr[d0 + 0], kv.x, sum);
        sum = fmaf(qr[d0 + 1], kv.y, sum);
        sum = fmaf(qr[d0 + 2], kv.z, sum);
        sum = fmaf(qr[d0 + 3], kv.w, sum);
      }
      s[j] = (diag && (kt * 64 + k > q_glob)) ? -1e30f : sum;
    }

    float mx = s[0];
#pragma unroll
    for (int j = 1; j < 16; j++) mx = fmaxf(mx, s[j]);
    mx = fmaxf(mx, __shfl_xor(mx, 1, 64));
    mx = fmaxf(mx, __shfl_xor(mx, 2, 64));
    const float m_new = fmaxf(m_i, mx);
    const float alpha = __expf(m_i - m_new);
    float lsum = 0.f;
    float* prow = &Psm[q * KSTR];
#pragma unroll
    for (int j = 0; j < 16; j++) {
      float p = __expf(s[j] - m_new);
      lsum += p;
      prow[dq + 4 * j] = p;
    }
    lsum += __shfl_xor(lsum, 1, 64);
    lsum += __shfl_xor(lsum, 2, 64);
    l_i = l_i * alpha + lsum;
    m_i = m_new;
#pragma unroll
    for (int i = 0; i < 16; i++) acc[i] *= alpha;
    __syncthreads();

    const float* pr = &Psm[q * KSTR];
    for (int k = 0; k < 64; k++) {
      float p = pr[k];
      const float* vp = &Vsm[k * KSTR + dq * 16];
#pragma unroll
      for (int d0 = 0; d0 < 16; d0 += 4) {
        float4 vv = *(const float4*)(vp + d0);
        acc[d0 + 0] = fmaf(p, vv.x, acc[d0 + 0]);
        acc[d0 + 1] = fmaf(p, vv.y, acc[d0 + 1]);
        acc[d0 + 2] = fmaf(p, vv.z, acc[d0 + 2]);
        acc[d0 + 3] = fmaf(p, vv.w, acc[d0 + 3]);
      }
    }
  }

  const float inv = 1.0f / l_i;
  ushort_t* yp = y + ((size_t)(b * T_SEQ + q_glob)) * CEMB + h * HDIM + dq * 16;
#pragma unroll
  for (int i = 0; i < 16; i++) yp[i] = f2b(acc[i] * inv);
}

// ---------- launcher ----------
extern "C" void kernel_launch(void* const* d_in, const int* in_sizes, int n_in,
                              void* d_out, int out_size, void* d_ws, size_t ws_size,
                              hipStream_t stream) {
  const float* x      = (const float*)d_in[0];  // [4,2048,768] fp32
  const float* w_attn = (const float*)d_in[1];  // [768,2304]
  const float* b_attn = (const float*)d_in[2];  // [2304]
  const float* w_proj = (const float*)d_in[3];  // [768,768]
  const float* b_proj = (const float*)d_in[4];  // [768]
  float* out = (float*)d_out;                   // [4,2048,768] fp32

  char* ws = (char*)d_ws;
  ushort_t* qkv = (ushort_t*)ws;                          // 8192*2304 bf16
  ushort_t* y   = qkv + (size_t)8192 * 2304;              // 8192*768
  ushort_t* xb  = y + (size_t)8192 * 768;                 // 8192*768 bf16 x
  ushort_t* wT  = xb + (size_t)8192 * 768;                // 2304*768 (w_attn^T)
  ushort_t* wpT = wT + (size_t)2304 * 768;                // 768*768  (w_proj^T)

  // x -> bf16 (8192*768 / 8 per thread = 786432 threads)
  cvt_x_k<<<3072, 256, 0, stream>>>(x, xb);
  // weights: transpose + convert
  transpose_cvt_k<<<dim3(C3 / 32, CEMB / 32), dim3(32, 8), 0, stream>>>(w_attn, wT, CEMB, C3);
  transpose_cvt_k<<<dim3(CEMB / 32, CEMB / 32), dim3(32, 8), 0, stream>>>(w_proj, wpT, CEMB, CEMB);

  // qkv = x @ w_attn + b_attn   (M=8192, N=2304, K=768), bf16 out
  gemm_bt<false><<<dim3(C3 / 128, 8192 / 128), 256, 0, stream>>>(xb, wT, b_attn, qkv, 8192, C3, CEMB);

  // flash attention -> y [B,T,C] bf16
  attn_k<<<dim3(T_SEQ / 64, NHEAD, BATCH), 256, 0, stream>>>(qkv, y);

  // out = y @ w_proj + b_proj   (M=8192, N=768, K=768), fp32 out
  gemm_bt<true><<<dim3(CEMB / 128, 8192 / 128), 256, 0, stream>>>(y, wpT, b_proj, out, 8192, CEMB, CEMB);
}

// Round 5
// 376.457 us; speedup vs baseline: 2.7464x; 2.7464x over previous
//
#include <hip/hip_runtime.h>
#include <stdint.h>

typedef unsigned short ushort_t;

#define T_SEQ 2048
#define BATCH 4
#define NHEAD 12
#define CEMB 768
#define HDIM 64
#define C3 2304

// ---------- bf16 helpers ----------
__device__ __forceinline__ float b2f(ushort_t u) {
  return __uint_as_float(((uint32_t)u) << 16);
}
__device__ __forceinline__ ushort_t f2b(float f) {
  uint32_t u = __float_as_uint(f);
  uint32_t r = (u + 0x7fffu + ((u >> 16) & 1u)) >> 16;  // RNE
  return (ushort_t)r;
}

// ---------- fp32 -> bf16 bulk convert (8 elems/thread) ----------
__global__ __launch_bounds__(256) void cvt_x_k(const float* __restrict__ in,
                                               ushort_t* __restrict__ out) {
  const int i = blockIdx.x * 256 + threadIdx.x;
  float4 a = ((const float4*)in)[2 * i];
  float4 b = ((const float4*)in)[2 * i + 1];
  union { ushort_t u[8]; uint4 v; } p;
  p.u[0] = f2b(a.x); p.u[1] = f2b(a.y); p.u[2] = f2b(a.z); p.u[3] = f2b(a.w);
  p.u[4] = f2b(b.x); p.u[5] = f2b(b.y); p.u[6] = f2b(b.z); p.u[7] = f2b(b.w);
  ((uint4*)out)[i] = p.v;
}

// ---------- fused transpose + fp32->bf16: out[c][r] = bf16(in[r][c]) ----------
__global__ void transpose_cvt_k(const float* __restrict__ in, ushort_t* __restrict__ out,
                                int R, int C) {
  __shared__ ushort_t tile[32][33];
  const int c0 = blockIdx.x * 32, r0 = blockIdx.y * 32;
  for (int i = threadIdx.y; i < 32; i += 8)
    tile[i][threadIdx.x] = f2b(in[(size_t)(r0 + i) * C + c0 + threadIdx.x]);
  __syncthreads();
  for (int i = threadIdx.y; i < 32; i += 8)
    out[(size_t)(c0 + i) * R + r0 + threadIdx.x] = tile[threadIdx.x][i];
}

// ---------- MFMA GEMM: C[M,N] = A[M,K] * Bt[N,K]^T + bias ----------
typedef __bf16 bf16x8 __attribute__((ext_vector_type(8)));
typedef float f32x4 __attribute__((ext_vector_type(4)));

template <bool OUTF>
__global__ __launch_bounds__(256) void gemm_bt(const ushort_t* __restrict__ A,
                                               const ushort_t* __restrict__ Bt,
                                               const float* __restrict__ bias,
                                               void* __restrict__ Cv,
                                               int M, int N, int K) {
  __shared__ ushort_t As[128 * 32];
  __shared__ ushort_t Bs[128 * 32];
  const int tid = threadIdx.x;
  const int m0 = blockIdx.y * 128, n0 = blockIdx.x * 128;
  const int wid = tid >> 6, lane = tid & 63;
  const int quad = lane >> 4, l15 = lane & 15;
  const int wm = (wid >> 1) * 64, wn = (wid & 1) * 64;
  f32x4 acc[4][4] = {};

  const int e0 = tid * 8;
  const int e1 = e0 + 2048;
  const int r0s = e0 >> 5, c0s = e0 & 31;
  const int r1s = e1 >> 5, c1s = e1 & 31;

  for (int k0 = 0; k0 < K; k0 += 32) {
    __syncthreads();
    *(uint4*)&As[e0] = *(const uint4*)&A[(size_t)(m0 + r0s) * K + k0 + c0s];
    *(uint4*)&As[e1] = *(const uint4*)&A[(size_t)(m0 + r1s) * K + k0 + c1s];
    *(uint4*)&Bs[e0] = *(const uint4*)&Bt[(size_t)(n0 + r0s) * K + k0 + c0s];
    *(uint4*)&Bs[e1] = *(const uint4*)&Bt[(size_t)(n0 + r1s) * K + k0 + c1s];
    __syncthreads();
    bf16x8 af[4], bfr[4];
#pragma unroll
    for (int t = 0; t < 4; t++)
      af[t] = *(const bf16x8*)&As[(wm + t * 16 + l15) * 32 + quad * 8];
#pragma unroll
    for (int t = 0; t < 4; t++)
      bfr[t] = *(const bf16x8*)&Bs[(wn + t * 16 + l15) * 32 + quad * 8];
#pragma unroll
    for (int tm = 0; tm < 4; tm++)
#pragma unroll
      for (int tn = 0; tn < 4; tn++)
        acc[tm][tn] = __builtin_amdgcn_mfma_f32_16x16x32_bf16(af[tm], bfr[tn], acc[tm][tn], 0, 0, 0);
  }

#pragma unroll
  for (int tm = 0; tm < 4; tm++) {
    const int row = m0 + wm + tm * 16 + quad * 4;
#pragma unroll
    for (int tn = 0; tn < 4; tn++) {
      const int col = n0 + wn + tn * 16 + l15;
      const float bv = bias[col];
#pragma unroll
      for (int rr = 0; rr < 4; rr++) {
        if constexpr (OUTF)
          ((float*)Cv)[(size_t)(row + rr) * N + col] = acc[tm][tn][rr] + bv;
        else
          ((ushort_t*)Cv)[(size_t)(row + rr) * N + col] = f2b(acc[tm][tn][rr] + bv);
      }
    }
  }
}

// ---------- MFMA flash attention, causal ----------
// Q-tile 128 (wave w owns q rows [qw, qw+32)), K-tile 64.
// S = Q*K^T via mfma_16x16x32_bf16 (A=Q regs, B=K LDS); online softmax in
// C-layout regs; P -> LDS (bf16) -> A-frags; PV with B = V^T (LDS).
#define QT 128
// Row stride for 64-key-wide LDS tiles. MUST be >= 64 (key dim); 72 keeps rows
// 16B-aligned (144 B) and makes A-frag b128 reads 2-way-per-bank (free, m136).
#define PSTR 72

__global__ __launch_bounds__(256) void attn_mfma_k(const ushort_t* __restrict__ qkv,
                                                   ushort_t* __restrict__ y) {
  __shared__ ushort_t KsmH[2 * 64 * 32];   // [half d][key][32] m97-style split
  __shared__ ushort_t Vt[64 * PSTR];       // [d][key], transposed V
  __shared__ ushort_t Plds[4][32 * PSTR];  // per-wave P [q_local][key]

  const int qti = (int)gridDim.x - 1 - (int)blockIdx.x;  // tail-first
  const int h = blockIdx.y, b = blockIdx.z;
  const int tid = threadIdx.x;
  const int w = tid >> 6, lane = tid & 63;
  const int quad = lane >> 4, l15 = lane & 15;
  const int qb = qti * QT;
  const int qw = qb + w * 32;  // this wave's first q row

  // Q fragments (A-layout): m-subtile, d-half
  bf16x8 aq[2][2];
#pragma unroll
  for (int m = 0; m < 2; m++)
#pragma unroll
    for (int kb = 0; kb < 2; kb++)
      aq[m][kb] = *(const bf16x8*)&qkv[((size_t)(b * T_SEQ + qw + m * 16 + l15)) * C3 +
                                       h * HDIM + kb * 32 + quad * 8];

  f32x4 o[2][4] = {};
  float mrow[2][4], lrow[2][4];
#pragma unroll
  for (int m = 0; m < 2; m++)
#pragma unroll
    for (int r = 0; r < 4; r++) { mrow[m][r] = -3e38f; lrow[m][r] = 0.f; }

  // staging thread mappings
  const int krow = tid >> 2, kseg = tid & 3;          // K: coalesced
  const int vkey = tid & 63, vd0 = (tid >> 6) * 16;   // V: bank-friendly scatter

  const int nkt = 2 * qti + 2;
  for (int kt = 0; kt < nkt; ++kt) {
    __syncthreads();  // previous iter's LDS reads done
    {
      const ushort_t* kp = qkv + ((size_t)(b * T_SEQ + kt * 64 + krow)) * C3 +
                           CEMB + h * HDIM + kseg * 8;
      uint4 ka = *(const uint4*)kp;
      uint4 kb_ = *(const uint4*)(kp + 32);
      ((uint4*)KsmH)[tid] = ka;          // linear -> conflict-free
      ((uint4*)KsmH)[tid + 256] = kb_;

      const ushort_t* vp = qkv + ((size_t)(b * T_SEQ + kt * 64 + vkey)) * C3 +
                           2 * CEMB + h * HDIM + vd0;
      uint4 v0 = *(const uint4*)vp;
      uint4 v1 = *(const uint4*)(vp + 8);
      union { ushort_t u[16]; uint4 v[2]; } vv;
      vv.v[0] = v0; vv.v[1] = v1;
#pragma unroll
      for (int j = 0; j < 16; j++) Vt[(vd0 + j) * PSTR + vkey] = vv.u[j];
    }
    __syncthreads();  // staging visible

    if (kt * 64 <= qw + 31) {  // wave has unmasked work in this key tile
      // ---- S = Q*K^T ----
      f32x4 s[2][4] = {};
      bf16x8 bk[4][2];
#pragma unroll
      for (int n = 0; n < 4; n++) {
        bk[n][0] = *(const bf16x8*)&KsmH[(n * 16 + l15) * 32 + quad * 8];
        bk[n][1] = *(const bf16x8*)&KsmH[2048 + (n * 16 + l15) * 32 + quad * 8];
      }
#pragma unroll
      for (int m = 0; m < 2; m++)
#pragma unroll
        for (int n = 0; n < 4; n++) {
          s[m][n] = __builtin_amdgcn_mfma_f32_16x16x32_bf16(aq[m][0], bk[n][0], s[m][n], 0, 0, 0);
          s[m][n] = __builtin_amdgcn_mfma_f32_16x16x32_bf16(aq[m][1], bk[n][1], s[m][n], 0, 0, 0);
        }

      // ---- causal mask (only near diagonal) ----
      if (kt * 64 + 63 > qw) {
#pragma unroll
        for (int m = 0; m < 2; m++)
#pragma unroll
          for (int n = 0; n < 4; n++) {
            const int keyg = kt * 64 + n * 16 + l15;
#pragma unroll
            for (int r = 0; r < 4; r++) {
              const int qg = qw + m * 16 + quad * 4 + r;
              if (keyg > qg) s[m][n][r] = -3e38f;
            }
          }
      }

      // ---- online softmax (rows live in (quad,reg); reduce over l15) ----
#pragma unroll
      for (int m = 0; m < 2; m++) {
        float al[4];
#pragma unroll
        for (int r = 0; r < 4; r++) {
          float v = fmaxf(fmaxf(s[m][0][r], s[m][1][r]), fmaxf(s[m][2][r], s[m][3][r]));
          v = fmaxf(v, __shfl_xor(v, 1, 64));
          v = fmaxf(v, __shfl_xor(v, 2, 64));
          v = fmaxf(v, __shfl_xor(v, 4, 64));
          v = fmaxf(v, __shfl_xor(v, 8, 64));
          const float mn = fmaxf(mrow[m][r], v);
          al[r] = __expf(0.125f * (mrow[m][r] - mn));  // 1/sqrt(64) folded in
          mrow[m][r] = mn;
          float lsum = 0.f;
#pragma unroll
          for (int n = 0; n < 4; n++) {
            float p = __expf(0.125f * (s[m][n][r] - mn));
            s[m][n][r] = p;
            lsum += p;
          }
          lsum += __shfl_xor(lsum, 1, 64);
          lsum += __shfl_xor(lsum, 2, 64);
          lsum += __shfl_xor(lsum, 4, 64);
          lsum += __shfl_xor(lsum, 8, 64);
          lrow[m][r] = lrow[m][r] * al[r] + lsum;
        }
#pragma unroll
        for (int nd = 0; nd < 4; nd++)
#pragma unroll
          for (int r = 0; r < 4; r++) o[m][nd][r] *= al[r];
        // P -> LDS (C-layout scatter, per-wave region)
#pragma unroll
        for (int n = 0; n < 4; n++)
#pragma unroll
          for (int r = 0; r < 4; r++)
            Plds[w][(m * 16 + quad * 4 + r) * PSTR + n * 16 + l15] = f2b(s[m][n][r]);
      }

      // in-wave DS ordering: writes committed before cross-lane reads
      asm volatile("s_waitcnt lgkmcnt(0)" ::: "memory");

      // ---- PV ----
      bf16x8 ap[2][2], bv[4][2];
#pragma unroll
      for (int m = 0; m < 2; m++)
#pragma unroll
        for (int kb = 0; kb < 2; kb++)
          ap[m][kb] = *(const bf16x8*)&Plds[w][(m * 16 + l15) * PSTR + kb * 32 + quad * 8];
#pragma unroll
      for (int nd = 0; nd < 4; nd++)
#pragma unroll
        for (int kb = 0; kb < 2; kb++)
          bv[nd][kb] = *(const bf16x8*)&Vt[(nd * 16 + l15) * PSTR + kb * 32 + quad * 8];
#pragma unroll
      for (int m = 0; m < 2; m++)
#pragma unroll
        for (int nd = 0; nd < 4; nd++) {
          o[m][nd] = __builtin_amdgcn_mfma_f32_16x16x32_bf16(ap[m][0], bv[nd][0], o[m][nd], 0, 0, 0);
          o[m][nd] = __builtin_amdgcn_mfma_f32_16x16x32_bf16(ap[m][1], bv[nd][1], o[m][nd], 0, 0, 0);
        }
    }
  }

  // ---- epilogue: y[b][q][h*64+d] = o / l ----
#pragma unroll
  for (int m = 0; m < 2; m++)
#pragma unroll
    for (int r = 0; r < 4; r++) {
      const int qg = qw + m * 16 + quad * 4 + r;
      const float inv = 1.0f / lrow[m][r];
      ushort_t* yp = y + ((size_t)(b * T_SEQ + qg)) * CEMB + h * HDIM + l15;
#pragma unroll
      for (int nd = 0; nd < 4; nd++) yp[nd * 16] = f2b(o[m][nd][r] * inv);
    }
}

// ---------- launcher ----------
extern "C" void kernel_launch(void* const* d_in, const int* in_sizes, int n_in,
                              void* d_out, int out_size, void* d_ws, size_t ws_size,
                              hipStream_t stream) {
  const float* x      = (const float*)d_in[0];  // [4,2048,768] fp32
  const float* w_attn = (const float*)d_in[1];  // [768,2304]
  const float* b_attn = (const float*)d_in[2];  // [2304]
  const float* w_proj = (const float*)d_in[3];  // [768,768]
  const float* b_proj = (const float*)d_in[4];  // [768]
  float* out = (float*)d_out;                   // [4,2048,768] fp32

  char* ws = (char*)d_ws;
  ushort_t* qkv = (ushort_t*)ws;                          // 8192*2304 bf16
  ushort_t* y   = qkv + (size_t)8192 * 2304;              // 8192*768
  ushort_t* xb  = y + (size_t)8192 * 768;                 // 8192*768 bf16 x
  ushort_t* wT  = xb + (size_t)8192 * 768;                // 2304*768 (w_attn^T)
  ushort_t* wpT = wT + (size_t)2304 * 768;                // 768*768  (w_proj^T)

  cvt_x_k<<<3072, 256, 0, stream>>>(x, xb);
  transpose_cvt_k<<<dim3(C3 / 32, CEMB / 32), dim3(32, 8), 0, stream>>>(w_attn, wT, CEMB, C3);
  transpose_cvt_k<<<dim3(CEMB / 32, CEMB / 32), dim3(32, 8), 0, stream>>>(w_proj, wpT, CEMB, CEMB);

  // qkv = x @ w_attn + b_attn   (M=8192, N=2304, K=768), bf16 out
  gemm_bt<false><<<dim3(C3 / 128, 8192 / 128), 256, 0, stream>>>(xb, wT, b_attn, qkv, 8192, C3, CEMB);

  // MFMA flash attention -> y [B,T,C] bf16
  attn_mfma_k<<<dim3(T_SEQ / QT, NHEAD, BATCH), 256, 0, stream>>>(qkv, y);

  // out = y @ w_proj + b_proj   (M=8192, N=768, K=768), fp32 out
  gemm_bt<true><<<dim3(CEMB / 128, 8192 / 128), 256, 0, stream>>>(y, wpT, b_proj, out, 8192, CEMB, CEMB);
}

// Round 6
// 334.318 us; speedup vs baseline: 3.0926x; 1.1260x over previous
//
#include <hip/hip_runtime.h>
#include <stdint.h>

typedef unsigned short ushort_t;

#define T_SEQ 2048
#define BATCH 4
#define NHEAD 12
#define CEMB 768
#define HDIM 64
#define C3 2304

// ---------- bf16 helpers ----------
__device__ __forceinline__ ushort_t f2b(float f) {
  uint32_t u = __float_as_uint(f);
  uint32_t r = (u + 0x7fffu + ((u >> 16) & 1u)) >> 16;  // RNE
  return (ushort_t)r;
}
__device__ __forceinline__ uint32_t f2b2(float lo, float hi) {
  return (uint32_t)f2b(lo) | ((uint32_t)f2b(hi) << 16);
}

// ---------- async global->LDS 16B ----------
typedef __attribute__((address_space(3))) unsigned int lds_u32_t;
typedef const __attribute__((address_space(1))) unsigned int glb_u32_t;
__device__ __forceinline__ void async_cp16(const void* g, void* l) {
  __builtin_amdgcn_global_load_lds((glb_u32_t*)g, (lds_u32_t*)l, 16, 0, 0);
}

// ---------- fp32 -> bf16 bulk convert (8 elems/thread) ----------
__global__ __launch_bounds__(256) void cvt_x_k(const float* __restrict__ in,
                                               ushort_t* __restrict__ out) {
  const int i = blockIdx.x * 256 + threadIdx.x;
  float4 a = ((const float4*)in)[2 * i];
  float4 b = ((const float4*)in)[2 * i + 1];
  union { ushort_t u[8]; uint4 v; } p;
  p.u[0] = f2b(a.x); p.u[1] = f2b(a.y); p.u[2] = f2b(a.z); p.u[3] = f2b(a.w);
  p.u[4] = f2b(b.x); p.u[5] = f2b(b.y); p.u[6] = f2b(b.z); p.u[7] = f2b(b.w);
  ((uint4*)out)[i] = p.v;
}

// ---------- fused transpose + fp32->bf16: out[c][r] = bf16(in[r][c]) ----------
__global__ void transpose_cvt_k(const float* __restrict__ in, ushort_t* __restrict__ out,
                                int R, int C) {
  __shared__ ushort_t tile[32][33];
  const int c0 = blockIdx.x * 32, r0 = blockIdx.y * 32;
  for (int i = threadIdx.y; i < 32; i += 8)
    tile[i][threadIdx.x] = f2b(in[(size_t)(r0 + i) * C + c0 + threadIdx.x]);
  __syncthreads();
  for (int i = threadIdx.y; i < 32; i += 8)
    out[(size_t)(c0 + i) * R + r0 + threadIdx.x] = tile[threadIdx.x][i];
}

// ---------- MFMA GEMM: C[M,N] = A[M,K] * Bt[N,K]^T + bias ----------
typedef __bf16 bf16x8 __attribute__((ext_vector_type(8)));
typedef float f32x4 __attribute__((ext_vector_type(4)));

template <bool OUTF>
__global__ __launch_bounds__(256) void gemm_bt(const ushort_t* __restrict__ A,
                                               const ushort_t* __restrict__ Bt,
                                               const float* __restrict__ bias,
                                               void* __restrict__ Cv,
                                               int M, int N, int K) {
  __shared__ ushort_t As[128 * 32];
  __shared__ ushort_t Bs[128 * 32];
  const int tid = threadIdx.x;
  const int m0 = blockIdx.y * 128, n0 = blockIdx.x * 128;
  const int wid = tid >> 6, lane = tid & 63;
  const int quad = lane >> 4, l15 = lane & 15;
  const int wm = (wid >> 1) * 64, wn = (wid & 1) * 64;
  f32x4 acc[4][4] = {};

  const int e0 = tid * 8;        // LDS elem offset; lane-linear 16B (required!)
  const int e1 = e0 + 2048;
  const int r0s = e0 >> 5, c0s = e0 & 31;
  const int r1s = e1 >> 5, c1s = e1 & 31;

  for (int k0 = 0; k0 < K; k0 += 32) {
    __syncthreads();
    async_cp16(&A[(size_t)(m0 + r0s) * K + k0 + c0s], &As[e0]);
    async_cp16(&A[(size_t)(m0 + r1s) * K + k0 + c1s], &As[e1]);
    async_cp16(&Bt[(size_t)(n0 + r0s) * K + k0 + c0s], &Bs[e0]);
    async_cp16(&Bt[(size_t)(n0 + r1s) * K + k0 + c1s], &Bs[e1]);
    __syncthreads();  // drains vmcnt (global_load_lds) per m97 structure
    bf16x8 af[4], bfr[4];
#pragma unroll
    for (int t = 0; t < 4; t++)
      af[t] = *(const bf16x8*)&As[(wm + t * 16 + l15) * 32 + quad * 8];
#pragma unroll
    for (int t = 0; t < 4; t++)
      bfr[t] = *(const bf16x8*)&Bs[(wn + t * 16 + l15) * 32 + quad * 8];
#pragma unroll
    for (int tm = 0; tm < 4; tm++)
#pragma unroll
      for (int tn = 0; tn < 4; tn++)
        acc[tm][tn] = __builtin_amdgcn_mfma_f32_16x16x32_bf16(af[tm], bfr[tn], acc[tm][tn], 0, 0, 0);
  }

#pragma unroll
  for (int tm = 0; tm < 4; tm++) {
    const int row = m0 + wm + tm * 16 + quad * 4;
#pragma unroll
    for (int tn = 0; tn < 4; tn++) {
      const int col = n0 + wn + tn * 16 + l15;
      const float bv = bias[col];
#pragma unroll
      for (int rr = 0; rr < 4; rr++) {
        if constexpr (OUTF)
          ((float*)Cv)[(size_t)(row + rr) * N + col] = acc[tm][tn][rr] + bv;
        else
          ((ushort_t*)Cv)[(size_t)(row + rr) * N + col] = f2b(acc[tm][tn][rr] + bv);
      }
    }
  }
}

// ---------- MFMA flash attention (S^T formulation), causal ----------
// Wave handles 32 q x 64 keys. S^T = K*Q^T: A=K (LDS), B=Q (regs);
// C-layout: col=q=l15, row=key=quad*4+r -> softmax needs only 2 shuffles/row
// and P[q][key] packs 4 keys/lane -> ds_write_b64. PV: A=P (LDS), B=V^T (LDS).
#define QT 128
#define KPAD 40  // K LDS row stride (elems): 80 B, 16B-aligned, 2-way banks
#define PSTR 72  // Vt/Plds row stride (elems): 144 B, 16B-aligned, 2-way banks

__global__ __launch_bounds__(256) void attn_mfma_k(const ushort_t* __restrict__ qkv,
                                                   ushort_t* __restrict__ y) {
  __shared__ ushort_t Ksm[2 * 64 * KPAD];  // [d-half][key][KPAD]
  __shared__ ushort_t Vt[64 * PSTR];       // [d][key]
  __shared__ ushort_t Plds[4][32 * PSTR];  // per-wave [q_local][key]

  const int qti = (int)gridDim.x - 1 - (int)blockIdx.x;
  const int h = blockIdx.y, b = blockIdx.z;
  const int tid = threadIdx.x;
  const int w = tid >> 6, lane = tid & 63;
  const int quad = lane >> 4, l15 = lane & 15;
  const int qw = qti * QT + w * 32;

  // Q fragments (B-operand layout == A-layout bytes): [q-subtile][d-half]
  bf16x8 qB[2][2];
#pragma unroll
  for (int n = 0; n < 2; n++)
#pragma unroll
    for (int kb = 0; kb < 2; kb++)
      qB[n][kb] = *(const bf16x8*)&qkv[((size_t)(b * T_SEQ + qw + n * 16 + l15)) * C3 +
                                       h * HDIM + kb * 32 + quad * 8];

  f32x4 o[2][4] = {};                    // [q-subtile][d-subtile]
  float m_i[2] = {-3e38f, -3e38f}, l_i[2] = {0.f, 0.f};

  const int krow = tid >> 2, kseg = tid & 3;
  const int vkey = tid & 63, vd0 = (tid >> 6) * 16;

  const int nkt = 2 * qti + 2;
  for (int kt = 0; kt < nkt; ++kt) {
    __syncthreads();
    {
      const ushort_t* kp = qkv + ((size_t)(b * T_SEQ + kt * 64 + krow)) * C3 +
                           CEMB + h * HDIM + kseg * 8;
      uint4 ka = *(const uint4*)kp;
      uint4 kb_ = *(const uint4*)(kp + 32);
      *(uint4*)&Ksm[krow * KPAD + kseg * 8] = ka;
      *(uint4*)&Ksm[64 * KPAD + krow * KPAD + kseg * 8] = kb_;

      const ushort_t* vp = qkv + ((size_t)(b * T_SEQ + kt * 64 + vkey)) * C3 +
                           2 * CEMB + h * HDIM + vd0;
      uint4 v0 = *(const uint4*)vp;
      uint4 v1 = *(const uint4*)(vp + 8);
      union { ushort_t u[16]; uint4 v[2]; } vv;
      vv.v[0] = v0; vv.v[1] = v1;
#pragma unroll
      for (int j = 0; j < 16; j++) Vt[(vd0 + j) * PSTR + vkey] = vv.u[j];
    }
    __syncthreads();

    if (kt * 64 <= qw + 31) {
      // ---- S^T = K*Q^T ----
      bf16x8 kA[4][2];
#pragma unroll
      for (int m = 0; m < 4; m++) {
        kA[m][0] = *(const bf16x8*)&Ksm[(m * 16 + l15) * KPAD + quad * 8];
        kA[m][1] = *(const bf16x8*)&Ksm[64 * KPAD + (m * 16 + l15) * KPAD + quad * 8];
      }
      f32x4 st[4][2] = {};  // [key-subtile][q-subtile]
#pragma unroll
      for (int m = 0; m < 4; m++)
#pragma unroll
        for (int n = 0; n < 2; n++) {
          st[m][n] = __builtin_amdgcn_mfma_f32_16x16x32_bf16(kA[m][0], qB[n][0], st[m][n], 0, 0, 0);
          st[m][n] = __builtin_amdgcn_mfma_f32_16x16x32_bf16(kA[m][1], qB[n][1], st[m][n], 0, 0, 0);
        }

      // ---- causal mask (near diagonal only) ----
      if (kt * 64 + 63 > qw) {
#pragma unroll
        for (int m = 0; m < 4; m++)
#pragma unroll
          for (int r = 0; r < 4; r++) {
            const int keyg = kt * 64 + m * 16 + quad * 4 + r;
#pragma unroll
            for (int n = 0; n < 2; n++) {
              const int qg = qw + n * 16 + l15;
              if (keyg > qg) st[m][n][r] = -3e38f;
            }
          }
      }

      // ---- online softmax: q on l15, keys in-lane + cross-quad ----
      float al[2];
#pragma unroll
      for (int n = 0; n < 2; n++) {
        float mx = st[0][n][0];
#pragma unroll
        for (int m = 0; m < 4; m++)
#pragma unroll
          for (int r = 0; r < 4; r++) mx = fmaxf(mx, st[m][n][r]);
        mx = fmaxf(mx, __shfl_xor(mx, 16, 64));
        mx = fmaxf(mx, __shfl_xor(mx, 32, 64));
        const float mn = fmaxf(m_i[n], mx);
        al[n] = __expf(0.125f * (m_i[n] - mn));  // 1/sqrt(64) folded in
        m_i[n] = mn;
        float ls = 0.f;
#pragma unroll
        for (int m = 0; m < 4; m++)
#pragma unroll
          for (int r = 0; r < 4; r++) {
            float p = __expf(0.125f * (st[m][n][r] - mn));
            st[m][n][r] = p;
            ls += p;
          }
        ls += __shfl_xor(ls, 16, 64);
        ls += __shfl_xor(ls, 32, 64);
        l_i[n] = l_i[n] * al[n] + ls;
      }
      // rescale O: alpha indexed by q=l15, O rows are q=quad*4+r -> broadcast
#pragma unroll
      for (int n = 0; n < 2; n++) {
        float ab[4];
#pragma unroll
        for (int r = 0; r < 4; r++) ab[r] = __shfl(al[n], quad * 4 + r, 64);
#pragma unroll
        for (int nd = 0; nd < 4; nd++)
#pragma unroll
          for (int r = 0; r < 4; r++) o[n][nd][r] *= ab[r];
        // P[q][key]: lane holds 4 consecutive keys -> one b64 per (m,n)
#pragma unroll
        for (int m = 0; m < 4; m++) {
          uint2 pk;
          pk.x = f2b2(st[m][n][0], st[m][n][1]);
          pk.y = f2b2(st[m][n][2], st[m][n][3]);
          *(uint2*)&Plds[w][(n * 16 + l15) * PSTR + m * 16 + quad * 4] = pk;
        }
      }

      // in-wave DS ordering: P writes committed before cross-lane reads
      asm volatile("s_waitcnt lgkmcnt(0)" ::: "memory");

      // ---- PV: O += P*V  (A=P, B=V^T) ----
      bf16x8 ap[2][2], bv[4][2];
#pragma unroll
      for (int n = 0; n < 2; n++)
#pragma unroll
        for (int kb = 0; kb < 2; kb++)
          ap[n][kb] = *(const bf16x8*)&Plds[w][(n * 16 + l15) * PSTR + kb * 32 + quad * 8];
#pragma unroll
      for (int nd = 0; nd < 4; nd++)
#pragma unroll
        for (int kb = 0; kb < 2; kb++)
          bv[nd][kb] = *(const bf16x8*)&Vt[(nd * 16 + l15) * PSTR + kb * 32 + quad * 8];
#pragma unroll
      for (int n = 0; n < 2; n++)
#pragma unroll
        for (int nd = 0; nd < 4; nd++) {
          o[n][nd] = __builtin_amdgcn_mfma_f32_16x16x32_bf16(ap[n][0], bv[nd][0], o[n][nd], 0, 0, 0);
          o[n][nd] = __builtin_amdgcn_mfma_f32_16x16x32_bf16(ap[n][1], bv[nd][1], o[n][nd], 0, 0, 0);
        }
    }
  }

  // ---- epilogue ----
#pragma unroll
  for (int n = 0; n < 2; n++) {
    const float inv = 1.0f / l_i[n];
#pragma unroll
    for (int r = 0; r < 4; r++) {
      const float iv = __shfl(inv, quad * 4 + r, 64);
      const int qg = qw + n * 16 + quad * 4 + r;
      ushort_t* yp = y + ((size_t)(b * T_SEQ + qg)) * CEMB + h * HDIM + l15;
#pragma unroll
      for (int nd = 0; nd < 4; nd++) yp[nd * 16] = f2b(o[n][nd][r] * iv);
    }
  }
}

// ---------- launcher ----------
extern "C" void kernel_launch(void* const* d_in, const int* in_sizes, int n_in,
                              void* d_out, int out_size, void* d_ws, size_t ws_size,
                              hipStream_t stream) {
  const float* x      = (const float*)d_in[0];  // [4,2048,768] fp32
  const float* w_attn = (const float*)d_in[1];  // [768,2304]
  const float* b_attn = (const float*)d_in[2];  // [2304]
  const float* w_proj = (const float*)d_in[3];  // [768,768]
  const float* b_proj = (const float*)d_in[4];  // [768]
  float* out = (float*)d_out;                   // [4,2048,768] fp32

  char* ws = (char*)d_ws;
  ushort_t* qkv = (ushort_t*)ws;                          // 8192*2304 bf16
  ushort_t* y   = qkv + (size_t)8192 * 2304;              // 8192*768
  ushort_t* xb  = y + (size_t)8192 * 768;                 // 8192*768 bf16 x
  ushort_t* wT  = xb + (size_t)8192 * 768;                // 2304*768 (w_attn^T)
  ushort_t* wpT = wT + (size_t)2304 * 768;                // 768*768  (w_proj^T)

  cvt_x_k<<<3072, 256, 0, stream>>>(x, xb);
  transpose_cvt_k<<<dim3(C3 / 32, CEMB / 32), dim3(32, 8), 0, stream>>>(w_attn, wT, CEMB, C3);
  transpose_cvt_k<<<dim3(CEMB / 32, CEMB / 32), dim3(32, 8), 0, stream>>>(w_proj, wpT, CEMB, CEMB);

  // qkv = x @ w_attn + b_attn   (M=8192, N=2304, K=768), bf16 out
  gemm_bt<false><<<dim3(C3 / 128, 8192 / 128), 256, 0, stream>>>(xb, wT, b_attn, qkv, 8192, C3, CEMB);

  // MFMA flash attention -> y [B,T,C] bf16
  attn_mfma_k<<<dim3(T_SEQ / QT, NHEAD, BATCH), 256, 0, stream>>>(qkv, y);

  // out = y @ w_proj + b_proj   (M=8192, N=768, K=768), fp32 out
  gemm_bt<true><<<dim3(CEMB / 128, 8192 / 128), 256, 0, stream>>>(y, wpT, b_proj, out, 8192, CEMB, CEMB);
}

// Round 7
// 286.576 us; speedup vs baseline: 3.6078x; 1.1666x over previous
//
#include <hip/hip_runtime.h>
#include <stdint.h>

typedef unsigned short ushort_t;

#define T_SEQ 2048
#define BATCH 4
#define NHEAD 12
#define CEMB 768
#define HDIM 64
#define C3 2304

// ---------- bf16 helpers ----------
__device__ __forceinline__ ushort_t f2b(float f) {
  uint32_t u = __float_as_uint(f);
  uint32_t r = (u + 0x7fffu + ((u >> 16) & 1u)) >> 16;  // RNE
  return (ushort_t)r;
}
__device__ __forceinline__ uint32_t f2b2(float lo, float hi) {
  return (uint32_t)f2b(lo) | ((uint32_t)f2b(hi) << 16);
}

// ---------- async global->LDS 16B ----------
typedef __attribute__((address_space(3))) unsigned int lds_u32_t;
typedef const __attribute__((address_space(1))) unsigned int glb_u32_t;
__device__ __forceinline__ void async_cp16(const void* g, void* l) {
  __builtin_amdgcn_global_load_lds((glb_u32_t*)g, (lds_u32_t*)l, 16, 0, 0);
}

// ---------- fp32 -> bf16 bulk convert (8 elems/thread) ----------
__global__ __launch_bounds__(256) void cvt_x_k(const float* __restrict__ in,
                                               ushort_t* __restrict__ out) {
  const int i = blockIdx.x * 256 + threadIdx.x;
  float4 a = ((const float4*)in)[2 * i];
  float4 b = ((const float4*)in)[2 * i + 1];
  union { ushort_t u[8]; uint4 v; } p;
  p.u[0] = f2b(a.x); p.u[1] = f2b(a.y); p.u[2] = f2b(a.z); p.u[3] = f2b(a.w);
  p.u[4] = f2b(b.x); p.u[5] = f2b(b.y); p.u[6] = f2b(b.z); p.u[7] = f2b(b.w);
  ((uint4*)out)[i] = p.v;
}

// ---------- fused transpose + fp32->bf16: out[c][r] = bf16(in[r][c]) ----------
__global__ void transpose_cvt_k(const float* __restrict__ in, ushort_t* __restrict__ out,
                                int R, int C) {
  __shared__ ushort_t tile[32][33];
  const int c0 = blockIdx.x * 32, r0 = blockIdx.y * 32;
  for (int i = threadIdx.y; i < 32; i += 8)
    tile[i][threadIdx.x] = f2b(in[(size_t)(r0 + i) * C + c0 + threadIdx.x]);
  __syncthreads();
  for (int i = threadIdx.y; i < 32; i += 8)
    out[(size_t)(c0 + i) * R + r0 + threadIdx.x] = tile[threadIdx.x][i];
}

// ---------- MFMA GEMM: C[M,N] = A[M,K] * Bt[N,K]^T + bias ----------
typedef __bf16 bf16x8 __attribute__((ext_vector_type(8)));
typedef float f32x4 __attribute__((ext_vector_type(4)));

template <bool OUTF>
__global__ __launch_bounds__(256) void gemm_bt(const ushort_t* __restrict__ A,
                                               const ushort_t* __restrict__ Bt,
                                               const float* __restrict__ bias,
                                               void* __restrict__ Cv,
                                               int M, int N, int K) {
  __shared__ ushort_t As[128 * 32];
  __shared__ ushort_t Bs[128 * 32];
  const int tid = threadIdx.x;
  const int m0 = blockIdx.y * 128, n0 = blockIdx.x * 128;
  const int wid = tid >> 6, lane = tid & 63;
  const int quad = lane >> 4, l15 = lane & 15;
  const int wm = (wid >> 1) * 64, wn = (wid & 1) * 64;
  f32x4 acc[4][4] = {};

  const int e0 = tid * 8;        // LDS elem offset; lane-linear 16B (required!)
  const int e1 = e0 + 2048;
  const int r0s = e0 >> 5, c0s = e0 & 31;
  const int r1s = e1 >> 5, c1s = e1 & 31;

  for (int k0 = 0; k0 < K; k0 += 32) {
    __syncthreads();
    async_cp16(&A[(size_t)(m0 + r0s) * K + k0 + c0s], &As[e0]);
    async_cp16(&A[(size_t)(m0 + r1s) * K + k0 + c1s], &As[e1]);
    async_cp16(&Bt[(size_t)(n0 + r0s) * K + k0 + c0s], &Bs[e0]);
    async_cp16(&Bt[(size_t)(n0 + r1s) * K + k0 + c1s], &Bs[e1]);
    __syncthreads();
    bf16x8 af[4], bfr[4];
#pragma unroll
    for (int t = 0; t < 4; t++)
      af[t] = *(const bf16x8*)&As[(wm + t * 16 + l15) * 32 + quad * 8];
#pragma unroll
    for (int t = 0; t < 4; t++)
      bfr[t] = *(const bf16x8*)&Bs[(wn + t * 16 + l15) * 32 + quad * 8];
#pragma unroll
    for (int tm = 0; tm < 4; tm++)
#pragma unroll
      for (int tn = 0; tn < 4; tn++)
        acc[tm][tn] = __builtin_amdgcn_mfma_f32_16x16x32_bf16(af[tm], bfr[tn], acc[tm][tn], 0, 0, 0);
  }

#pragma unroll
  for (int tm = 0; tm < 4; tm++) {
    const int row = m0 + wm + tm * 16 + quad * 4;
#pragma unroll
    for (int tn = 0; tn < 4; tn++) {
      const int col = n0 + wn + tn * 16 + l15;
      const float bv = bias[col];
#pragma unroll
      for (int rr = 0; rr < 4; rr++) {
        if constexpr (OUTF)
          ((float*)Cv)[(size_t)(row + rr) * N + col] = acc[tm][tn][rr] + bv;
        else
          ((ushort_t*)Cv)[(size_t)(row + rr) * N + col] = f2b(acc[tm][tn][rr] + bv);
      }
    }
  }
}

// ---------- MFMA flash attention (S^T form), causal, balanced strips ----------
// Block s in [0,16); wave w owns the 32-q strip at qw = w*512 + s*32.
// Block work nkt(s) in [25,32] -> near-uniform (kills the causal tail).
// S^T = K*Q^T (A=K LDS, B=Q regs); softmax rows on l15; P->LDS b64; PV B=V^T.
// Next K/V tile prefetched into registers during compute (latency overlap).
#define KPAD 40  // K LDS row stride (elems): 80 B, 16B-aligned, 2-way banks
#define PSTR 72  // Vt/Plds row stride (elems): 144 B, 16B-aligned, 2-way banks

__global__ __launch_bounds__(256) void attn_mfma_k(const ushort_t* __restrict__ qkv,
                                                   ushort_t* __restrict__ y) {
  __shared__ ushort_t Ksm[2 * 64 * KPAD];  // [d-half][key][KPAD]
  __shared__ ushort_t Vt[64 * PSTR];       // [d][key]
  __shared__ ushort_t Plds[4][32 * PSTR];  // per-wave [q_local][key]

  const int s = blockIdx.x;                // 0..15
  const int h = blockIdx.y, b = blockIdx.z;
  const int tid = threadIdx.x;
  const int w = tid >> 6, lane = tid & 63;
  const int quad = lane >> 4, l15 = lane & 15;
  const int qw = w * 512 + s * 32;         // this wave's 32-q strip

  // Q fragments (B-operand layout == A-layout bytes): [q-subtile][d-half]
  bf16x8 qB[2][2];
#pragma unroll
  for (int n = 0; n < 2; n++)
#pragma unroll
    for (int kb = 0; kb < 2; kb++)
      qB[n][kb] = *(const bf16x8*)&qkv[((size_t)(b * T_SEQ + qw + n * 16 + l15)) * C3 +
                                       h * HDIM + kb * 32 + quad * 8];

  f32x4 o[2][4] = {};                    // [q-subtile][d-subtile]
  float m_i[2] = {-3e38f, -3e38f}, l_i[2] = {0.f, 0.f};

  // staging thread mappings
  const int krow = tid >> 2, kseg = tid & 3;          // K: coalesced b128
  const int vpair = tid & 31, vd0 = (tid >> 5) * 8;   // V: key pair, 8-d octet

  const int nkt = ((1567 + s * 32) >> 6) + 1;         // 25..32 tiles

  // register prefetch of tile 0
  uint4 pK0, pK1, pV0, pV1;
  {
    const ushort_t* kp = qkv + ((size_t)(b * T_SEQ + krow)) * C3 + CEMB + h * HDIM + kseg * 8;
    pK0 = *(const uint4*)kp;
    pK1 = *(const uint4*)(kp + 32);
    const ushort_t* vp = qkv + ((size_t)(b * T_SEQ + 2 * vpair)) * C3 + 2 * CEMB + h * HDIM + vd0;
    pV0 = *(const uint4*)vp;
    pV1 = *(const uint4*)(vp + C3);
  }

  for (int kt = 0; kt < nkt; ++kt) {
    __syncthreads();  // previous iter's LDS reads done
    // ---- commit prefetched tile to LDS ----
    *(uint4*)&Ksm[krow * KPAD + kseg * 8] = pK0;
    *(uint4*)&Ksm[64 * KPAD + krow * KPAD + kseg * 8] = pK1;
    {
      union { ushort_t u[8]; uint4 v; } v0, v1;
      v0.v = pV0; v1.v = pV1;
#pragma unroll
      for (int j = 0; j < 8; j++)
        *(uint32_t*)&Vt[(vd0 + j) * PSTR + 2 * vpair] =
            (uint32_t)v0.u[j] | ((uint32_t)v1.u[j] << 16);
    }
    // ---- prefetch next tile (overlaps with compute below) ----
    if (kt + 1 < nkt) {
      const ushort_t* kp = qkv + ((size_t)(b * T_SEQ + (kt + 1) * 64 + krow)) * C3 +
                           CEMB + h * HDIM + kseg * 8;
      pK0 = *(const uint4*)kp;
      pK1 = *(const uint4*)(kp + 32);
      const ushort_t* vp = qkv + ((size_t)(b * T_SEQ + (kt + 1) * 64 + 2 * vpair)) * C3 +
                           2 * CEMB + h * HDIM + vd0;
      pV0 = *(const uint4*)vp;
      pV1 = *(const uint4*)(vp + C3);
    }
    __syncthreads();  // staging visible

    if (kt * 64 <= qw + 31) {
      // ---- S^T = K*Q^T ----
      bf16x8 kA[4][2];
#pragma unroll
      for (int m = 0; m < 4; m++) {
        kA[m][0] = *(const bf16x8*)&Ksm[(m * 16 + l15) * KPAD + quad * 8];
        kA[m][1] = *(const bf16x8*)&Ksm[64 * KPAD + (m * 16 + l15) * KPAD + quad * 8];
      }
      f32x4 st[4][2] = {};  // [key-subtile][q-subtile]
#pragma unroll
      for (int m = 0; m < 4; m++)
#pragma unroll
        for (int n = 0; n < 2; n++) {
          st[m][n] = __builtin_amdgcn_mfma_f32_16x16x32_bf16(kA[m][0], qB[n][0], st[m][n], 0, 0, 0);
          st[m][n] = __builtin_amdgcn_mfma_f32_16x16x32_bf16(kA[m][1], qB[n][1], st[m][n], 0, 0, 0);
        }

      // ---- causal mask (near diagonal only) ----
      if (kt * 64 + 63 > qw) {
#pragma unroll
        for (int m = 0; m < 4; m++)
#pragma unroll
          for (int r = 0; r < 4; r++) {
            const int keyg = kt * 64 + m * 16 + quad * 4 + r;
#pragma unroll
            for (int n = 0; n < 2; n++) {
              const int qg = qw + n * 16 + l15;
              if (keyg > qg) st[m][n][r] = -3e38f;
            }
          }
      }

      // ---- online softmax: q on l15, keys in-lane + cross-quad ----
      float al[2];
#pragma unroll
      for (int n = 0; n < 2; n++) {
        float mx = st[0][n][0];
#pragma unroll
        for (int m = 0; m < 4; m++)
#pragma unroll
          for (int r = 0; r < 4; r++) mx = fmaxf(mx, st[m][n][r]);
        mx = fmaxf(mx, __shfl_xor(mx, 16, 64));
        mx = fmaxf(mx, __shfl_xor(mx, 32, 64));
        const float mn = fmaxf(m_i[n], mx);
        al[n] = __expf(0.125f * (m_i[n] - mn));  // 1/sqrt(64) folded in
        m_i[n] = mn;
        float ls = 0.f;
#pragma unroll
        for (int m = 0; m < 4; m++)
#pragma unroll
          for (int r = 0; r < 4; r++) {
            float p = __expf(0.125f * (st[m][n][r] - mn));
            st[m][n][r] = p;
            ls += p;
          }
        ls += __shfl_xor(ls, 16, 64);
        ls += __shfl_xor(ls, 32, 64);
        l_i[n] = l_i[n] * al[n] + ls;
      }
      // rescale O (alpha on l15 -> broadcast to quad*4+r rows) + P -> LDS
#pragma unroll
      for (int n = 0; n < 2; n++) {
        float ab[4];
#pragma unroll
        for (int r = 0; r < 4; r++) ab[r] = __shfl(al[n], quad * 4 + r, 64);
#pragma unroll
        for (int nd = 0; nd < 4; nd++)
#pragma unroll
          for (int r = 0; r < 4; r++) o[n][nd][r] *= ab[r];
#pragma unroll
        for (int m = 0; m < 4; m++) {
          uint2 pk;
          pk.x = f2b2(st[m][n][0], st[m][n][1]);
          pk.y = f2b2(st[m][n][2], st[m][n][3]);
          *(uint2*)&Plds[w][(n * 16 + l15) * PSTR + m * 16 + quad * 4] = pk;
        }
      }

      // in-wave DS ordering: P writes committed before cross-lane reads
      asm volatile("s_waitcnt lgkmcnt(0)" ::: "memory");

      // ---- PV: O += P*V  (A=P, B=V^T) ----
      bf16x8 ap[2][2], bv[4][2];
#pragma unroll
      for (int n = 0; n < 2; n++)
#pragma unroll
        for (int kb = 0; kb < 2; kb++)
          ap[n][kb] = *(const bf16x8*)&Plds[w][(n * 16 + l15) * PSTR + kb * 32 + quad * 8];
#pragma unroll
      for (int nd = 0; nd < 4; nd++)
#pragma unroll
        for (int kb = 0; kb < 2; kb++)
          bv[nd][kb] = *(const bf16x8*)&Vt[(nd * 16 + l15) * PSTR + kb * 32 + quad * 8];
#pragma unroll
      for (int n = 0; n < 2; n++)
#pragma unroll
        for (int nd = 0; nd < 4; nd++) {
          o[n][nd] = __builtin_amdgcn_mfma_f32_16x16x32_bf16(ap[n][0], bv[nd][0], o[n][nd], 0, 0, 0);
          o[n][nd] = __builtin_amdgcn_mfma_f32_16x16x32_bf16(ap[n][1], bv[nd][1], o[n][nd], 0, 0, 0);
        }
    }
  }

  // ---- epilogue ----
#pragma unroll
  for (int n = 0; n < 2; n++) {
    const float inv = 1.0f / l_i[n];
#pragma unroll
    for (int r = 0; r < 4; r++) {
      const float iv = __shfl(inv, quad * 4 + r, 64);
      const int qg = qw + n * 16 + quad * 4 + r;
      ushort_t* yp = y + ((size_t)(b * T_SEQ + qg)) * CEMB + h * HDIM + l15;
#pragma unroll
      for (int nd = 0; nd < 4; nd++) yp[nd * 16] = f2b(o[n][nd][r] * iv);
    }
  }
}

// ---------- launcher ----------
extern "C" void kernel_launch(void* const* d_in, const int* in_sizes, int n_in,
                              void* d_out, int out_size, void* d_ws, size_t ws_size,
                              hipStream_t stream) {
  const float* x      = (const float*)d_in[0];  // [4,2048,768] fp32
  const float* w_attn = (const float*)d_in[1];  // [768,2304]
  const float* b_attn = (const float*)d_in[2];  // [2304]
  const float* w_proj = (const float*)d_in[3];  // [768,768]
  const float* b_proj = (const float*)d_in[4];  // [768]
  float* out = (float*)d_out;                   // [4,2048,768] fp32

  char* ws = (char*)d_ws;
  ushort_t* qkv = (ushort_t*)ws;                          // 8192*2304 bf16
  ushort_t* y   = qkv + (size_t)8192 * 2304;              // 8192*768
  ushort_t* xb  = y + (size_t)8192 * 768;                 // 8192*768 bf16 x
  ushort_t* wT  = xb + (size_t)8192 * 768;                // 2304*768 (w_attn^T)
  ushort_t* wpT = wT + (size_t)2304 * 768;                // 768*768  (w_proj^T)

  cvt_x_k<<<3072, 256, 0, stream>>>(x, xb);
  transpose_cvt_k<<<dim3(C3 / 32, CEMB / 32), dim3(32, 8), 0, stream>>>(w_attn, wT, CEMB, C3);
  transpose_cvt_k<<<dim3(CEMB / 32, CEMB / 32), dim3(32, 8), 0, stream>>>(w_proj, wpT, CEMB, CEMB);

  // qkv = x @ w_attn + b_attn   (M=8192, N=2304, K=768), bf16 out
  gemm_bt<false><<<dim3(C3 / 128, 8192 / 128), 256, 0, stream>>>(xb, wT, b_attn, qkv, 8192, C3, CEMB);

  // MFMA flash attention -> y [B,T,C] bf16
  attn_mfma_k<<<dim3(16, NHEAD, BATCH), 256, 0, stream>>>(qkv, y);

  // out = y @ w_proj + b_proj   (M=8192, N=768, K=768), fp32 out
  gemm_bt<true><<<dim3(CEMB / 128, 8192 / 128), 256, 0, stream>>>(y, wpT, b_proj, out, 8192, CEMB, CEMB);
}